// Round 14
// baseline (180.084 us; speedup 1.0000x reference)
//
#include <hip/hip_runtime.h>
#include <stdint.h>

typedef unsigned int u32;
typedef unsigned long long u64;
typedef unsigned short u16;
typedef unsigned char u8;

#define NPTS 8192
#define CAP 20           // list rows per point (lambda~3.1, P(>20)~1e-13)
#define UNR 8            // unconditional rows loaded in k_nms round 0
#define INRG 4           // register in-seg slots
#define NSEG 4
#define SEGSZ 2048
#define NBRB (32 * 33)   // 1056 neighbor tiles
#define RANKB 1024       // rank blocks (8 points each)
#define TOTB (NBRB + RANKB)

// ---------------------------------------------------------------------------
// k_build: ONE kernel, two INDEPENDENT halves (no cross-half sync, no fences).
//  blocks 0..1055: neighbor lists in ORIGINAL index space. Triangular tiles
//    (R:256 rows i, C:128 cols j, C<=2R+1) cover each unordered pair once;
//    direction decided per hit by score-bit compare (tie: smaller index
//    wins), suppressed side's list gets the edge. Reverse edges (~1.5/point)
//    are scattered atomics -- cheap. d2<64 <=> sqrt(d2)<8 exactly in f32.
//  blocks 1056..2079: rank of 8 points each (256 thr = 8 pts x 32 slices of
//    256 keys). Uniform loop: threshold compare + tie-count (no divergent
//    boundary path); exact stable rank = #{kq>kp} + #{kq==kp, q<p}.
//    Writes sorted_id / rank_of / ss.
// ---------------------------------------------------------------------------
__global__ __launch_bounds__(256) void k_build(const float* __restrict__ coords,
                                               const float* __restrict__ scores,
                                               u32* __restrict__ cnt,
                                               u16* __restrict__ nbr,
                                               u32* __restrict__ sorted_id,
                                               u32* __restrict__ rank_of,
                                               float* __restrict__ ss) {
  __shared__ u32 smem[NPTS];  // nbr-half uses 384 words; rank-half all 8192
  int b = blockIdx.x, t = threadIdx.x;

  if (b < NBRB) {
    // ---------------- neighbor half ----------------
    float* qx = (float*)smem;
    float* qy = (float*)smem + 128;
    u32* qs = smem + 256;
    int R = (int)((__fsqrt_rn(4.0f * (float)b + 1.0f) - 1.0f) * 0.5f);
    while ((R + 1) * (R + 2) <= b) ++R;
    while (R * (R + 1) > b) --R;
    int C = b - R * (R + 1);
    int q0 = C << 7;
    int i = (R << 8) + t;
    if (t < 128) {
      int q = q0 + t;
      qx[t] = coords[2 * q];
      qy[t] = coords[2 * q + 1];
    } else {
      int u = t - 128;
      qs[u] = __float_as_uint(scores[q0 + u]);
    }
    __syncthreads();

    float x = coords[2 * i], y = coords[2 * i + 1];
    u32 si = __float_as_uint(scores[i]);
    int jlim = 128;
    int dC = C - 2 * R;
    if (dC >= 0) {                 // diagonal chunks: enforce q < i
      jlim = t - (dC << 7);
      if (jlim < 0) jlim = 0;
      if (jlim > 128) jlim = 128;
    }
    const float4* x4 = (const float4*)qx;
    const float4* y4 = (const float4*)qy;
    for (int jg = 0; jg < 4; ++jg) {
      int base = jg << 5;
      int v = jlim - base;
      u32 gm = (v >= 32) ? 0xFFFFFFFFu : ((v <= 0) ? 0u : ((1u << v) - 1u));
      u32 m = 0;
#pragma unroll
      for (int j4 = 0; j4 < 8; ++j4) {
        float4 xv = x4[(base >> 2) + j4];
        float4 yv = y4[(base >> 2) + j4];
        // mirror reference arithmetic: sub, mul, mul, add (no fma)
        float dx0 = __fsub_rn(x, xv.x), dy0 = __fsub_rn(y, yv.x);
        float dx1 = __fsub_rn(x, xv.y), dy1 = __fsub_rn(y, yv.y);
        float dx2 = __fsub_rn(x, xv.z), dy2 = __fsub_rn(y, yv.z);
        float dx3 = __fsub_rn(x, xv.w), dy3 = __fsub_rn(y, yv.w);
        if (__fadd_rn(__fmul_rn(dx0, dx0), __fmul_rn(dy0, dy0)) < 64.0f) m |= 1u << (4 * j4 + 0);
        if (__fadd_rn(__fmul_rn(dx1, dx1), __fmul_rn(dy1, dy1)) < 64.0f) m |= 1u << (4 * j4 + 1);
        if (__fadd_rn(__fmul_rn(dx2, dx2), __fmul_rn(dy2, dy2)) < 64.0f) m |= 1u << (4 * j4 + 2);
        if (__fadd_rn(__fmul_rn(dx3, dx3), __fmul_rn(dy3, dy3)) < 64.0f) m |= 1u << (4 * j4 + 3);
      }
      m &= gm;
      while (m) {  // rare: ~6.3 in-radius pairs per point total
        int j2 = __builtin_ctz(m);
        m &= m - 1;
        int q = q0 + base + j2;
        u32 sj = qs[base + j2];
        // q < i always here, so tie (sj==si) => q higher priority
        if (sj >= si) {       // q suppresses i
          u32 sl = atomicAdd(&cnt[i], 1u);
          if (sl < CAP) nbr[sl * NPTS + i] = (u16)q;
        } else {              // i suppresses q (scattered, ~1.5/point)
          u32 sl = atomicAdd(&cnt[q], 1u);
          if (sl < CAP) nbr[sl * NPTS + q] = (u16)i;
        }
      }
    }
  } else {
    // ---------------- rank half ----------------
    u32* skey = smem;
    int bi = b - NBRB;
    for (int k = t; k < NPTS; k += 256) skey[k] = __float_as_uint(scores[k]);
    __syncthreads();

    int g = t >> 5;         // point 0..7
    int s = t & 31;         // slice 0..31 (256 keys each)
    int p = bi * 8 + g;
    u32 kp = skey[p];
    int sp = p >> 8;        // slice containing p
    const uint4* k4 = (const uint4*)skey;
    int b4 = s << 6;
    u32 a = (s < sp) ? kp - 1u : kp;  // below: count >= (via > kp-1); else >
    u32 c = 0, tc = 0;
    int qb = s << 8;
#pragma unroll 4
    for (int j = 0; j < 64; ++j) {
      int jj = (j + s) & 63;          // rotate across bank groups
      uint4 kv = k4[b4 + jj];
      int q = qb + (jj << 2);
      c += (kv.x > a) + (kv.y > a) + (kv.z > a) + (kv.w > a);
      tc += (kv.x == kp && q + 0 < p) + (kv.y == kp && q + 1 < p) +
            (kv.z == kp && q + 2 < p) + (kv.w == kp && q + 3 < p);
    }
    if (s < sp && kp == 0) c += 256;  // kp-1 underflow fixup (>=0 is all)
    if (s == sp) c += tc;             // in-slice ties below p
    c += __shfl_xor(c, 1);
    c += __shfl_xor(c, 2);
    c += __shfl_xor(c, 4);
    c += __shfl_xor(c, 8);
    c += __shfl_xor(c, 16);
    if (s == 0) {
      sorted_id[c] = (u32)p;
      rank_of[p] = c;
      ss[c] = scores[p];  // bitwise copy keeps output exact
    }
  }
}

// ---------------------------------------------------------------------------
// k_nms: r13's proven fixpoint (1024 thr, 2 pts/thread, 4x2048 segments,
// triple-pass Gauss-Seidel, rotating 4-slot flag, 1 barrier/round) adapted
// to original-space lists: round 0 translates neighbors via rank_of gathers
// (rows prefetched one segment ahead; masked index keeps poison rows
// in-bounds). In-seg suppressor ranks: 4 register slots + 4 LDS-ext slots
// (covers P(in-seg<=8) ~ 99.6%) + ultra-rare global-translate fallback.
// All edges point low rank -> high rank, so prefix segments are FINAL and
// zero-flip exit certifies the unique fixpoint = exact greedy.
// ---------------------------------------------------------------------------
__global__ __launch_bounds__(1024) void k_nms(const u32* __restrict__ cnt,
                                              const u16* __restrict__ nbr,
                                              const u32* __restrict__ rank_of,
                                              const u32* __restrict__ sorted_id,
                                              const float* __restrict__ ss,
                                              float* __restrict__ out) {
  __shared__ u8 keep[NPTS];
  __shared__ u16 inext[2048][4];  // ext in-seg slots, seg-local index
  __shared__ int slot[4];
  int t = threadIdx.x;

  // prefetch segment 0
  u32 iA_n = sorted_id[t], iB_n = sorted_id[1024 + t];
  u32 cA_n = cnt[iA_n], cB_n = cnt[iB_n];
  u16 eA_n[UNR], eB_n[UNR];
#pragma unroll
  for (int n = 0; n < UNR; ++n) {
    eA_n[n] = nbr[n * NPTS + iA_n];
    eB_n[n] = nbr[n * NPTS + iB_n];
  }

  for (int s = 0; s < NSEG; ++s) {
    int segbase = s << 11;
    int pA = segbase + t, pB = segbase + 1024 + t;
    u32 iA = iA_n, iB = iB_n;
    u32 cA = cA_n > CAP ? CAP : cA_n;
    u32 cB = cB_n > CAP ? CAP : cB_n;
    u16 eA[UNR], eB[UNR];
#pragma unroll
    for (int n = 0; n < UNR; ++n) { eA[n] = eA_n[n]; eB[n] = eB_n[n]; }

    if (s < NSEG - 1) {  // issue next segment's loads now (hidden by rounds)
      int nb = segbase + SEGSZ;
      iA_n = sorted_id[nb + t];
      iB_n = sorted_id[nb + 1024 + t];
      cA_n = cnt[iA_n];
      cB_n = cnt[iB_n];
#pragma unroll
      for (int n = 0; n < UNR; ++n) {
        eA_n[n] = nbr[n * NPTS + iA_n];
        eB_n[n] = nbr[n * NPTS + iB_n];
      }
    }

    // ---- translate rows to rank space (independent gathers, one latency)
    u32 rA[UNR], rB[UNR];
#pragma unroll
    for (int n = 0; n < UNR; ++n) {
      rA[n] = rank_of[eA[n] & (NPTS - 1)];  // mask: poison rows stay in-bounds
      rB[n] = rank_of[eB[n] & (NPTS - 1)];
    }

    // ---- round 0: classify (prefix = FINAL keep bits; in-seg -> slots)
    bool supA = false, supB = false;
    u32 cinA = 0, cinB = 0;
    u16 rgA[INRG], rgB[INRG], exA[4], exB[4];
#pragma unroll
    for (int n = 0; n < INRG; ++n) { rgA[n] = 0xFFFF; rgB[n] = 0xFFFF; }
#pragma unroll
    for (int n = 0; n < 4; ++n) { exA[n] = 0xFFFF; exB[n] = 0xFFFF; }
#pragma unroll
    for (int n = 0; n < UNR; ++n) {
      if ((u32)n < cA) {
        u32 rq = rA[n];
        if (rq < (u32)segbase) supA |= (keep[rq] != 0);
        else {
          if (cinA < 4) rgA[cinA] = (u16)rq;
          else if (cinA < 8) exA[cinA - 4] = (u16)rq;
          cinA++;
        }
      }
      if ((u32)n < cB) {
        u32 rq = rB[n];
        if (rq < (u32)segbase) supB |= (keep[rq] != 0);
        else {
          if (cinB < 4) rgB[cinB] = (u16)rq;
          else if (cinB < 8) exB[cinB - 4] = (u16)rq;
          cinB++;
        }
      }
    }
    for (u32 n = UNR; n < cA; ++n) {  // tail ~4%: round-0 only
      u32 rq = rank_of[nbr[n * NPTS + iA] & (NPTS - 1)];
      if (rq < (u32)segbase) supA |= (keep[rq] != 0);
      else {
        if (cinA < 4) rgA[cinA] = (u16)rq;
        else if (cinA < 8) exA[cinA - 4] = (u16)rq;
        cinA++;
      }
    }
    for (u32 n = UNR; n < cB; ++n) {
      u32 rq = rank_of[nbr[n * NPTS + iB] & (NPTS - 1)];
      if (rq < (u32)segbase) supB |= (keep[rq] != 0);
      else {
        if (cinB < 4) rgB[cinB] = (u16)rq;
        else if (cinB < 8) exB[cinB - 4] = (u16)rq;
        cinB++;
      }
    }
    keep[pA] = supA ? (u8)0 : (u8)1;
    keep[pB] = supB ? (u8)0 : (u8)1;
#pragma unroll
    for (int n = 0; n < 4; ++n) {
      inext[t][n] = exA[n];
      inext[1024 + t][n] = exB[n];
    }
    bool actA = !supA && cinA > 0;
    bool actB = !supB && cinB > 0;
    bool extA = cinA > INRG, extB = cinB > INRG;
    bool fbA = cinA > 8, fbB = cinB > 8;  // ultra-rare full fallback
    if (t < 4) slot[t] = 0;
    __syncthreads();

    // ---- eval rounds: triple-pass Gauss-Seidel, 1 barrier/round ----
    for (int r = 1; r <= SEGSZ + 2; ++r) {
      if (t == 0) slot[(r + 2) & 3] = 0;
      bool flip = false;
#pragma unroll
      for (int pass = 0; pass < 3; ++pass) {
        if (actA) {
          bool dead = false;
          if (rgA[0] != 0xFFFF) dead |= (keep[rgA[0]] != 0);
          if (rgA[1] != 0xFFFF) dead |= (keep[rgA[1]] != 0);
          if (rgA[2] != 0xFFFF) dead |= (keep[rgA[2]] != 0);
          if (rgA[3] != 0xFFFF) dead |= (keep[rgA[3]] != 0);
          if (extA) {
            if (inext[t][0] != 0xFFFF) dead |= (keep[inext[t][0]] != 0);
            if (inext[t][1] != 0xFFFF) dead |= (keep[inext[t][1]] != 0);
            if (inext[t][2] != 0xFFFF) dead |= (keep[inext[t][2]] != 0);
            if (inext[t][3] != 0xFFFF) dead |= (keep[inext[t][3]] != 0);
          }
          if (fbA) {
            for (u32 n = 0; n < cA; ++n) {
              u32 rq = rank_of[nbr[n * NPTS + iA] & (NPTS - 1)];
              if (rq >= (u32)segbase) dead |= (keep[rq] != 0);
            }
          }
          u8 a = dead ? (u8)0 : (u8)1;
          if (keep[pA] != a) { keep[pA] = a; flip = true; }
        }
        if (actB) {
          bool dead = false;
          if (rgB[0] != 0xFFFF) dead |= (keep[rgB[0]] != 0);
          if (rgB[1] != 0xFFFF) dead |= (keep[rgB[1]] != 0);
          if (rgB[2] != 0xFFFF) dead |= (keep[rgB[2]] != 0);
          if (rgB[3] != 0xFFFF) dead |= (keep[rgB[3]] != 0);
          if (extB) {
            if (inext[1024 + t][0] != 0xFFFF) dead |= (keep[inext[1024 + t][0]] != 0);
            if (inext[1024 + t][1] != 0xFFFF) dead |= (keep[inext[1024 + t][1]] != 0);
            if (inext[1024 + t][2] != 0xFFFF) dead |= (keep[inext[1024 + t][2]] != 0);
            if (inext[1024 + t][3] != 0xFFFF) dead |= (keep[inext[1024 + t][3]] != 0);
          }
          if (fbB) {
            for (u32 n = 0; n < cB; ++n) {
              u32 rq = rank_of[nbr[n * NPTS + iB] & (NPTS - 1)];
              if (rq >= (u32)segbase) dead |= (keep[rq] != 0);
            }
          }
          u8 a = dead ? (u8)0 : (u8)1;
          if (keep[pB] != a) { keep[pB] = a; flip = true; }
        }
      }
      if (flip) slot[r & 3] = 1;
      __syncthreads();
      if (slot[r & 3] == 0) break;  // full round w/o flips: exact fixpoint
    }
  }

  // epilogue: keep mask (original order) + suppressed scores (rank order)
  for (int k = t; k < NPTS; k += 1024) {
    u8 kp = keep[k];
    out[sorted_id[k]] = kp ? 1.0f : 0.0f;
    out[NPTS + k] = kp ? ss[k] : 0.0f;
  }
}

// ---------------------------------------------------------------------------
extern "C" void kernel_launch(void* const* d_in, const int* in_sizes, int n_in,
                              void* d_out, int out_size, void* d_ws, size_t ws_size,
                              hipStream_t stream) {
  const float* coords = (const float*)d_in[0];  // [N,2]
  const float* scores = (const float*)d_in[1];  // [N]
  float* out = (float*)d_out;                   // [N keep | N suppressed scores]

  char* ws = (char*)d_ws;
  size_t off = 0;
  u16* nbr       = (u16*)(ws + off); off += (size_t)CAP * NPTS * 2;  // 320K
  u32* sorted_id = (u32*)(ws + off); off += (size_t)NPTS * 4;        // 32K
  u32* rank_of   = (u32*)(ws + off); off += (size_t)NPTS * 4;        // 32K
  float* ss      = (float*)(ws + off); off += (size_t)NPTS * 4;      // 32K
  u32* cnt       = (u32*)(ws + off); off += (size_t)NPTS * 4;        // 32K

  hipMemsetAsync(cnt, 0, (size_t)NPTS * 4, stream);
  k_build<<<TOTB, 256, 0, stream>>>(coords, scores, cnt, nbr, sorted_id,
                                    rank_of, ss);
  k_nms<<<1, 1024, 0, stream>>>(cnt, nbr, rank_of, sorted_id, ss, out);
}